// Round 1
// baseline (411.098 us; speedup 1.0000x reference)
//
#include <hip/hip_runtime.h>
#include <hip/hip_bf16.h>
#include <math.h>

#define N 8192
#define ZD 128

// ---------------------------------------------------------------------------
// k1: Z = relu(h @ W1 + b1) @ W2 + b2   (8192x64 -> 64 -> 128), fp32.
// Also initializes sums[i] = 1.0 (the fill_diagonal(1) contribution).
// ---------------------------------------------------------------------------
__global__ __launch_bounds__(256) void k1_mlp(
    const float* __restrict__ h, const float* __restrict__ W1,
    const float* __restrict__ b1, const float* __restrict__ W2,
    const float* __restrict__ b2, float* __restrict__ Z,
    float* __restrict__ sums)
{
    __shared__ float W1s[64][65];
    __shared__ float W2s[64][129];
    __shared__ float hs[64][65];
    __shared__ float Ts[64][65];
    __shared__ float b1s[64];
    __shared__ float b2s[128];
    const int tid = threadIdx.x;
    const int row0 = blockIdx.x * 64;

    int g = blockIdx.x * 256 + tid;
    if (g < N) sums[g] = 1.0f;

    for (int e = tid; e < 64 * 64; e += 256) W1s[e >> 6][e & 63] = W1[e];
    for (int e = tid; e < 64 * 128; e += 256) W2s[e >> 7][e & 127] = W2[e];
    for (int e = tid; e < 64 * 64; e += 256) hs[e >> 6][e & 63] = h[(size_t)row0 * 64 + e];
    if (tid < 64) b1s[tid] = b1[tid];
    if (tid < 128) b2s[tid] = b2[tid];
    __syncthreads();

    for (int o = tid; o < 64 * 64; o += 256) {
        int r = o >> 6, c = o & 63;
        float s = b1s[c];
        #pragma unroll
        for (int k = 0; k < 64; ++k) s = fmaf(hs[r][k], W1s[k][c], s);
        Ts[r][c] = fmaxf(s, 0.0f);
    }
    __syncthreads();
    for (int o = tid; o < 64 * 128; o += 256) {
        int r = o >> 7, c = o & 127;
        float s = b2s[c];
        #pragma unroll
        for (int k = 0; k < 64; ++k) s = fmaf(Ts[r][k], W2s[k][c], s);
        Z[(size_t)(row0 + r) * ZD + c] = s;
    }
}

// ---------------------------------------------------------------------------
// k3: upper-triangle tiles (ti <= tj), 128x128 per block, 256 threads,
// 8x8 per-thread fp32 register blocking, K=128 in 4 chunks of BK=32.
// Writes logits at [i,j] and transposed [j,i]; computes v = sigmoid(gumbel+L)
// into the adj region (upper tiles only, diag-masked); accumulates row sums.
// ---------------------------------------------------------------------------
__global__ __launch_bounds__(256) void k3_main(
    const float* __restrict__ Z, const float* __restrict__ noise,
    float* __restrict__ logits, float* __restrict__ vbuf,
    float* __restrict__ sums)
{
    const int tj = blockIdx.x, ti = blockIdx.y;
    if (ti > tj) return;
    const bool diag = (ti == tj);

    __shared__ float smem[8448];      // As[32][132] + Bs[32][132]; reused as Cs[64][129]
    __shared__ float rs[128], cs[128];
    float (*As)[132] = (float(*)[132])smem;
    float (*Bs)[132] = (float(*)[132])(smem + 32 * 132);

    const int tid = threadIdx.x;
    const int tn = tid & 15, tm = tid >> 4;
    const int i0 = ti * 128, j0 = tj * 128;

    if (tid < 128) { rs[tid] = 0.0f; cs[tid] = 0.0f; }

    float acc[8][8] = {};
    const int r = tid >> 3;
    const int k4 = (tid & 7) << 2;
    for (int k0 = 0; k0 < ZD; k0 += 32) {
        __syncthreads();
        #pragma unroll
        for (int p = 0; p < 4; ++p) {
            int m = r + p * 32;
            float4 av = *(const float4*)&Z[(size_t)(i0 + m) * ZD + k0 + k4];
            As[k4 + 0][m] = av.x; As[k4 + 1][m] = av.y;
            As[k4 + 2][m] = av.z; As[k4 + 3][m] = av.w;
            float4 bv = *(const float4*)&Z[(size_t)(j0 + m) * ZD + k0 + k4];
            Bs[k4 + 0][m] = bv.x; Bs[k4 + 1][m] = bv.y;
            Bs[k4 + 2][m] = bv.z; Bs[k4 + 3][m] = bv.w;
        }
        __syncthreads();
        #pragma unroll 4
        for (int kk = 0; kk < 32; ++kk) {
            float a[8], b[8];
            *(float4*)&a[0] = *(const float4*)&As[kk][tm * 8];
            *(float4*)&a[4] = *(const float4*)&As[kk][tm * 8 + 4];
            *(float4*)&b[0] = *(const float4*)&Bs[kk][tn * 8];
            *(float4*)&b[4] = *(const float4*)&Bs[kk][tn * 8 + 4];
            #pragma unroll
            for (int i = 0; i < 8; ++i)
                #pragma unroll
                for (int j = 0; j < 8; ++j)
                    acc[i][j] = fmaf(a[i], b[j], acc[i][j]);
        }
    }
    __syncthreads();

    // ---- logits direct write [i,j] ----
    #pragma unroll
    for (int i = 0; i < 8; ++i) {
        const size_t grow = (size_t)(i0 + tm * 8 + i) * N + j0 + tn * 8;
        *(float4*)&logits[grow]     = make_float4(acc[i][0], acc[i][1], acc[i][2], acc[i][3]);
        *(float4*)&logits[grow + 4] = make_float4(acc[i][4], acc[i][5], acc[i][6], acc[i][7]);
    }

    // ---- v = sigmoid(logit(eps) + L), row/col partial sums ----
    float csum[8] = {};
    #pragma unroll
    for (int i = 0; i < 8; ++i) {
        const int lr = tm * 8 + i;
        const size_t grow = (size_t)(i0 + lr) * N + j0 + tn * 8;
        float4 u0 = *(const float4*)&noise[grow];
        float4 u1 = *(const float4*)&noise[grow + 4];
        float u[8] = {u0.x, u0.y, u0.z, u0.w, u1.x, u1.y, u1.z, u1.w};
        float vv[8];
        float rsum = 0.0f;
        #pragma unroll
        for (int j = 0; j < 8; ++j) {
            const int lc = tn * 8 + j;
            float eps = fmaf(-0.9998f, u[j], 0.9999f);   // eps in [1e-4, 1-1e-4]
            float om  = fmaf( 0.9998f, u[j], 0.0001f);   // 1 - eps
            float gate = __logf(eps) - __logf(om) + acc[i][j];
            float v = 1.0f / (1.0f + __expf(-gate));
            if (diag && lr >= lc) v = 0.0f;   // strict upper triangle only
            vv[j] = v;
            rsum += v;
            csum[j] += v;
        }
        *(float4*)&vbuf[grow]     = make_float4(vv[0], vv[1], vv[2], vv[3]);
        *(float4*)&vbuf[grow + 4] = make_float4(vv[4], vv[5], vv[6], vv[7]);
        atomicAdd(&rs[lr], rsum);
    }
    #pragma unroll
    for (int j = 0; j < 8; ++j) atomicAdd(&cs[tn * 8 + j], csum[j]);
    __syncthreads();
    if (tid < 128) {
        if (diag) {
            atomicAdd(&sums[i0 + tid], rs[tid] + cs[tid]);
        } else {
            atomicAdd(&sums[i0 + tid], rs[tid]);
            atomicAdd(&sums[j0 + tid], cs[tid]);
        }
    }

    // ---- logits transposed write [j,i] via LDS staging ----
    if (!diag) {
        float (*Cs)[129] = (float(*)[129])smem;
        #pragma unroll
        for (int half = 0; half < 2; ++half) {
            __syncthreads();
            if ((tn >> 3) == half) {
                #pragma unroll
                for (int j = 0; j < 8; ++j)
                    #pragma unroll
                    for (int i = 0; i < 8; ++i)
                        Cs[(tn & 7) * 8 + j][tm * 8 + i] = acc[i][j];
            }
            __syncthreads();
            for (int it = 0; it < 32; ++it) {
                int w = tid + it * 256;
                int c = w >> 7, m = w & 127;
                logits[(size_t)(j0 + half * 64 + c) * N + i0 + m] = Cs[c][m];
            }
        }
    }
}

// ---------------------------------------------------------------------------
// k4: d = rsqrt(rowsum)
// ---------------------------------------------------------------------------
__global__ void k4_dvec(const float* __restrict__ sums, float* __restrict__ dvec)
{
    int i = blockIdx.x * 256 + threadIdx.x;
    if (i < N) dvec[i] = rsqrtf(sums[i]);
}

// ---------------------------------------------------------------------------
// k5: in-place normalize: adj[i,j] = v * d_i * d_j, mirror to [j,i],
// diagonal = d_i^2. Upper-triangle tiles only.
// ---------------------------------------------------------------------------
__global__ __launch_bounds__(256) void k5_norm(
    float* __restrict__ adj, const float* __restrict__ dvec)
{
    const int tj = blockIdx.x, ti = blockIdx.y;
    if (ti > tj) return;
    const bool diag = (ti == tj);
    __shared__ float T[128][65];
    const int tid = threadIdx.x;
    const int i0 = ti * 128, j0 = tj * 128;

    for (int it = 0; it < 16; ++it) {
        int w = tid + it * 256;
        int m = w >> 5;
        int n4 = (w & 31) << 2;
        size_t idx = (size_t)(i0 + m) * N + j0 + n4;
        float4 v4 = *(const float4*)&adj[idx];
        float dm = dvec[i0 + m];
        float4 o;
        o.x = v4.x * dm * dvec[j0 + n4 + 0];
        o.y = v4.y * dm * dvec[j0 + n4 + 1];
        o.z = v4.z * dm * dvec[j0 + n4 + 2];
        o.w = v4.w * dm * dvec[j0 + n4 + 3];
        *(float4*)&adj[idx] = o;   // diag tile: lower/diag components are 0, fixed below
        T[n4 + 0][m] = o.x; T[n4 + 1][m] = o.y;
        T[n4 + 2][m] = o.z; T[n4 + 3][m] = o.w;
    }
    __syncthreads();
    for (int it = 0; it < 64; ++it) {
        int w = tid + it * 256;
        int c = w >> 7, m = w & 127;
        if (!diag || m < c)
            adj[(size_t)(j0 + c) * N + i0 + m] = T[c][m];
    }
    if (diag && tid < 128) {
        float dm = dvec[i0 + tid];
        adj[(size_t)(i0 + tid) * N + i0 + tid] = dm * dm;
    }
}

// ---------------------------------------------------------------------------
extern "C" void kernel_launch(void* const* d_in, const int* in_sizes, int n_in,
                              void* d_out, int out_size, void* d_ws, size_t ws_size,
                              hipStream_t stream)
{
    const float* h     = (const float*)d_in[0];
    const float* W1    = (const float*)d_in[1];
    const float* b1    = (const float*)d_in[2];
    const float* W2    = (const float*)d_in[3];
    const float* b2    = (const float*)d_in[4];
    const float* noise = (const float*)d_in[5];

    float* adj    = (float*)d_out;                 // output 0: adj_norm [N,N]
    float* logits = adj + (size_t)N * N;           // output 1: adj_logits [N,N]

    float* Z    = (float*)d_ws;                    // [N, 128] fp32 = 4 MiB
    float* sums = Z + (size_t)N * ZD;              // [N]
    float* dvec = sums + N;                        // [N]

    k1_mlp<<<128, 256, 0, stream>>>(h, W1, b1, W2, b2, Z, sums);
    dim3 grid2(64, 64);
    k3_main<<<grid2, 256, 0, stream>>>(Z, noise, logits, adj, sums);
    k4_dvec<<<32, 256, 0, stream>>>(sums, dvec);
    k5_norm<<<grid2, 256, 0, stream>>>(adj, dvec);
}

// Round 2
// 376.460 us; speedup vs baseline: 1.0920x; 1.0920x over previous
//
#include <hip/hip_runtime.h>
#include <hip/hip_bf16.h>
#include <math.h>

#define N 8192
#define ZD 128

typedef __attribute__((ext_vector_type(8))) short bf16x8;
typedef __attribute__((ext_vector_type(4))) float f32x4;

// ---------------------------------------------------------------------------
// k1: Z = relu(h @ W1 + b1) @ W2 + b2 (fp32), stored as bf16 hi/lo split.
// Also initializes sums[i] = 1.0 (the fill_diagonal(1) contribution).
// ---------------------------------------------------------------------------
__global__ __launch_bounds__(256) void k1_mlp(
    const float* __restrict__ h, const float* __restrict__ W1,
    const float* __restrict__ b1, const float* __restrict__ W2,
    const float* __restrict__ b2, unsigned short* __restrict__ Zh,
    unsigned short* __restrict__ Zl, float* __restrict__ sums)
{
    __shared__ float W1s[64][65];
    __shared__ float W2s[64][129];
    __shared__ float hs[64][65];
    __shared__ float Ts[64][65];
    __shared__ float b1s[64];
    __shared__ float b2s[128];
    const int tid = threadIdx.x;
    const int row0 = blockIdx.x * 64;

    int g = blockIdx.x * 256 + tid;
    if (g < N) sums[g] = 1.0f;

    for (int e = tid; e < 64 * 64; e += 256) W1s[e >> 6][e & 63] = W1[e];
    for (int e = tid; e < 64 * 128; e += 256) W2s[e >> 7][e & 127] = W2[e];
    for (int e = tid; e < 64 * 64; e += 256) hs[e >> 6][e & 63] = h[(size_t)row0 * 64 + e];
    if (tid < 64) b1s[tid] = b1[tid];
    if (tid < 128) b2s[tid] = b2[tid];
    __syncthreads();

    for (int o = tid; o < 64 * 64; o += 256) {
        int r = o >> 6, c = o & 63;
        float s = b1s[c];
        #pragma unroll
        for (int k = 0; k < 64; ++k) s = fmaf(hs[r][k], W1s[k][c], s);
        Ts[r][c] = fmaxf(s, 0.0f);
    }
    __syncthreads();
    for (int o = tid; o < 64 * 128; o += 256) {
        int r = o >> 7, c = o & 127;
        float s = b2s[c];
        #pragma unroll
        for (int k = 0; k < 64; ++k) s = fmaf(Ts[r][k], W2s[k][c], s);
        size_t idx = (size_t)(row0 + r) * ZD + c;
        __hip_bfloat16 hb = __float2bfloat16(s);
        float hf = __bfloat162float(hb);
        __hip_bfloat16 lb = __float2bfloat16(s - hf);
        Zh[idx] = *reinterpret_cast<unsigned short*>(&hb);
        Zl[idx] = *reinterpret_cast<unsigned short*>(&lb);
    }
}

// ---------------------------------------------------------------------------
// k3: upper-triangle tiles (ti <= tj), 128x128 per block, 4 waves.
// bf16x2 split MFMA GEMM (3 passes of 16x16x32), operands direct from L2.
// Epilogue: LDS-staged in two 64-col halves -> coalesced float4 writes of
// logits [i,j], transposed [j,i], v = sigmoid(gumbel+L) into vbuf, row/col sums.
// ---------------------------------------------------------------------------
__global__ __launch_bounds__(256, 2) void k3_main(
    const unsigned short* __restrict__ Zh, const unsigned short* __restrict__ Zl,
    const float* __restrict__ noise, float* __restrict__ logits,
    float* __restrict__ vbuf, float* __restrict__ sums)
{
    const int tj = blockIdx.x, ti = blockIdx.y;
    if (ti > tj) return;
    const bool diag = (ti == tj);

    __shared__ float T[128][65];
    __shared__ float rs[128], cs[128];

    const int tid = threadIdx.x;
    const int lane = tid & 63;
    const int w = tid >> 6;
    const int wr = w >> 1, wc = w & 1;
    const int fr = lane & 15;     // fragment row (m/n within 16)
    const int kg = lane >> 4;     // k-group 0..3
    const int i0 = ti * 128, j0 = tj * 128;

    if (tid < 128) { rs[tid] = 0.0f; cs[tid] = 0.0f; }

    const unsigned short* Ahp = Zh + (size_t)(i0 + wr * 64) * ZD;
    const unsigned short* Alp = Zl + (size_t)(i0 + wr * 64) * ZD;
    const unsigned short* Bhp = Zh + (size_t)(j0 + wc * 64) * ZD;
    const unsigned short* Blp = Zl + (size_t)(j0 + wc * 64) * ZD;

    f32x4 acc[4][4];
    #pragma unroll
    for (int mf = 0; mf < 4; ++mf)
        #pragma unroll
        for (int nf = 0; nf < 4; ++nf)
            acc[mf][nf] = (f32x4)0.0f;

    #pragma unroll
    for (int kc = 0; kc < 4; ++kc) {
        const int ko = kc * 32 + kg * 8;
        bf16x8 ah[4], al[4], bh[4], bl[4];
        #pragma unroll
        for (int mf = 0; mf < 4; ++mf) {
            size_t off = (size_t)(mf * 16 + fr) * ZD + ko;
            ah[mf] = *(const bf16x8*)(Ahp + off);
            al[mf] = *(const bf16x8*)(Alp + off);
            bh[mf] = *(const bf16x8*)(Bhp + off);
            bl[mf] = *(const bf16x8*)(Blp + off);
        }
        #pragma unroll
        for (int mf = 0; mf < 4; ++mf)
            #pragma unroll
            for (int nf = 0; nf < 4; ++nf) {
                acc[mf][nf] = __builtin_amdgcn_mfma_f32_16x16x32_bf16(al[mf], bh[nf], acc[mf][nf], 0, 0, 0);
                acc[mf][nf] = __builtin_amdgcn_mfma_f32_16x16x32_bf16(ah[mf], bl[nf], acc[mf][nf], 0, 0, 0);
                acc[mf][nf] = __builtin_amdgcn_mfma_f32_16x16x32_bf16(ah[mf], bh[nf], acc[mf][nf], 0, 0, 0);
            }
    }

    // ---- epilogue in two 64-column halves ----
    const int c4 = (tid & 15) * 4;        // local col group within half
    const int rbase = tid >> 4;           // 0..15

    #pragma unroll
    for (int half = 0; half < 2; ++half) {
        __syncthreads();   // previous half's readers done / rs,cs init visible
        if (wc == half) {
            #pragma unroll
            for (int mf = 0; mf < 4; ++mf)
                #pragma unroll
                for (int nf = 0; nf < 4; ++nf)
                    #pragma unroll
                    for (int r = 0; r < 4; ++r)
                        T[wr * 64 + mf * 16 + (lane >> 4) * 4 + r][nf * 16 + fr] = acc[mf][nf][r];
        }
        __syncthreads();

        float4 csum = make_float4(0.f, 0.f, 0.f, 0.f);
        for (int it = 0; it < 8; ++it) {
            const int r = rbase + it * 16;
            float4 L4 = *(const float4*)&T[r][c4];
            const size_t g = (size_t)(i0 + r) * N + j0 + half * 64 + c4;
            *(float4*)&logits[g] = L4;
            float4 u4 = *(const float4*)&noise[g];
            float vv[4];
            float rsum = 0.0f;
            const float* up = &u4.x;
            const float* Lp = &L4.x;
            float* cp = &csum.x;
            #pragma unroll
            for (int e = 0; e < 4; ++e) {
                float u = up[e];
                float eps = fmaf(-0.9998f, u, 0.9999f);   // eps in [1e-4, 1-1e-4]
                float om  = fmaf( 0.9998f, u, 0.0001f);   // 1 - eps
                float gate = __logf(eps) - __logf(om) + Lp[e];
                float v = 1.0f / (1.0f + __expf(-gate));
                if (diag && r >= half * 64 + c4 + e) v = 0.0f;  // strict upper
                vv[e] = v;
                rsum += v;
                cp[e] += v;
            }
            *(float4*)&vbuf[g] = make_float4(vv[0], vv[1], vv[2], vv[3]);
            rsum += __shfl_xor(rsum, 8, 16);
            rsum += __shfl_xor(rsum, 4, 16);
            rsum += __shfl_xor(rsum, 2, 16);
            rsum += __shfl_xor(rsum, 1, 16);
            if ((tid & 15) == 0) atomicAdd(&rs[r], rsum);
        }
        #pragma unroll
        for (int e = 0; e < 4; ++e)
            atomicAdd(&cs[half * 64 + c4 + e], (&csum.x)[e]);

        if (!diag) {
            for (int it = 0; it < 8; ++it) {
                const int idx = tid + it * 256;     // 0..2047
                const int c = idx >> 5;             // 0..63
                const int m4 = (idx & 31) * 4;
                float4 o = make_float4(T[m4][c], T[m4 + 1][c], T[m4 + 2][c], T[m4 + 3][c]);
                *(float4*)&logits[(size_t)(j0 + half * 64 + c) * N + i0 + m4] = o;
            }
        }
    }

    __syncthreads();
    if (tid < 128) {
        if (diag) {
            atomicAdd(&sums[i0 + tid], rs[tid] + cs[tid]);
        } else {
            atomicAdd(&sums[i0 + tid], rs[tid]);
            atomicAdd(&sums[j0 + tid], cs[tid]);
        }
    }
}

// ---------------------------------------------------------------------------
// k4: d = rsqrt(rowsum)
// ---------------------------------------------------------------------------
__global__ void k4_dvec(const float* __restrict__ sums, float* __restrict__ dvec)
{
    int i = blockIdx.x * 256 + threadIdx.x;
    if (i < N) dvec[i] = rsqrtf(sums[i]);
}

// ---------------------------------------------------------------------------
// k5: in-place normalize: adj[i,j] = v * d_i * d_j, mirror to [j,i],
// diagonal = d_i^2. Upper-triangle tiles only.
// ---------------------------------------------------------------------------
__global__ __launch_bounds__(256) void k5_norm(
    float* __restrict__ adj, const float* __restrict__ dvec)
{
    const int tj = blockIdx.x, ti = blockIdx.y;
    if (ti > tj) return;
    const bool diag = (ti == tj);
    __shared__ float T[128][65];
    const int tid = threadIdx.x;
    const int i0 = ti * 128, j0 = tj * 128;

    for (int it = 0; it < 16; ++it) {
        int w = tid + it * 256;
        int m = w >> 5;
        int n4 = (w & 31) << 2;
        size_t idx = (size_t)(i0 + m) * N + j0 + n4;
        float4 v4 = *(const float4*)&adj[idx];
        float dm = dvec[i0 + m];
        float4 o;
        o.x = v4.x * dm * dvec[j0 + n4 + 0];
        o.y = v4.y * dm * dvec[j0 + n4 + 1];
        o.z = v4.z * dm * dvec[j0 + n4 + 2];
        o.w = v4.w * dm * dvec[j0 + n4 + 3];
        *(float4*)&adj[idx] = o;   // diag tile: lower/diag components are 0, fixed below
        T[n4 + 0][m] = o.x; T[n4 + 1][m] = o.y;
        T[n4 + 2][m] = o.z; T[n4 + 3][m] = o.w;
    }
    __syncthreads();
    for (int it = 0; it < 64; ++it) {
        int w = tid + it * 256;
        int c = w >> 7, m = w & 127;
        if (!diag || m < c)
            adj[(size_t)(j0 + c) * N + i0 + m] = T[c][m];
    }
    if (diag && tid < 128) {
        float dm = dvec[i0 + tid];
        adj[(size_t)(i0 + tid) * N + i0 + tid] = dm * dm;
    }
}

// ---------------------------------------------------------------------------
extern "C" void kernel_launch(void* const* d_in, const int* in_sizes, int n_in,
                              void* d_out, int out_size, void* d_ws, size_t ws_size,
                              hipStream_t stream)
{
    const float* h     = (const float*)d_in[0];
    const float* W1    = (const float*)d_in[1];
    const float* b1    = (const float*)d_in[2];
    const float* W2    = (const float*)d_in[3];
    const float* b2    = (const float*)d_in[4];
    const float* noise = (const float*)d_in[5];

    float* adj    = (float*)d_out;                 // output 0: adj_norm [N,N]
    float* logits = adj + (size_t)N * N;           // output 1: adj_logits [N,N]

    unsigned short* Zh = (unsigned short*)d_ws;            // [N,128] bf16 = 2 MiB
    unsigned short* Zl = Zh + (size_t)N * ZD;              // [N,128] bf16 = 2 MiB
    float* sums = (float*)(Zl + (size_t)N * ZD);           // [N]
    float* dvec = sums + N;                                // [N]

    k1_mlp<<<128, 256, 0, stream>>>(h, W1, b1, W2, b2, Zh, Zl, sums);
    dim3 grid2(64, 64);
    k3_main<<<grid2, 256, 0, stream>>>(Zh, Zl, noise, logits, adj, sums);
    k4_dvec<<<32, 256, 0, stream>>>(sums, dvec);
    k5_norm<<<grid2, 256, 0, stream>>>(adj, dvec);
}

// Round 3
// 334.783 us; speedup vs baseline: 1.2280x; 1.1245x over previous
//
#include <hip/hip_runtime.h>
#include <hip/hip_bf16.h>
#include <math.h>

#define N 8192
#define ZD 128

typedef __attribute__((ext_vector_type(8))) _Float16 f16x8;
typedef __attribute__((ext_vector_type(4))) float f32x4;

// ---------------------------------------------------------------------------
// k1: Z = relu(h @ W1 + b1) @ W2 + b2 (fp32), stored as f16.
// Also initializes sums[i] = 1.0 (the fill_diagonal(1) contribution).
// ---------------------------------------------------------------------------
__global__ __launch_bounds__(256) void k1_mlp(
    const float* __restrict__ h, const float* __restrict__ W1,
    const float* __restrict__ b1, const float* __restrict__ W2,
    const float* __restrict__ b2, _Float16* __restrict__ Zf,
    float* __restrict__ sums)
{
    __shared__ float W1s[64][65];
    __shared__ float W2s[64][129];
    __shared__ float hs[64][65];
    __shared__ float Ts[64][65];
    __shared__ float b1s[64];
    __shared__ float b2s[128];
    const int tid = threadIdx.x;
    const int row0 = blockIdx.x * 64;

    int g = blockIdx.x * 256 + tid;
    if (g < N) sums[g] = 1.0f;

    for (int e = tid; e < 64 * 64; e += 256) W1s[e >> 6][e & 63] = W1[e];
    for (int e = tid; e < 64 * 128; e += 256) W2s[e >> 7][e & 127] = W2[e];
    for (int e = tid; e < 64 * 64; e += 256) hs[e >> 6][e & 63] = h[(size_t)row0 * 64 + e];
    if (tid < 64) b1s[tid] = b1[tid];
    if (tid < 128) b2s[tid] = b2[tid];
    __syncthreads();

    for (int o = tid; o < 64 * 64; o += 256) {
        int r = o >> 6, c = o & 63;
        float s = b1s[c];
        #pragma unroll
        for (int k = 0; k < 64; ++k) s = fmaf(hs[r][k], W1s[k][c], s);
        Ts[r][c] = fmaxf(s, 0.0f);
    }
    __syncthreads();
    for (int o = tid; o < 64 * 128; o += 256) {
        int r = o >> 7, c = o & 127;
        float s = b2s[c];
        #pragma unroll
        for (int k = 0; k < 64; ++k) s = fmaf(Ts[r][k], W2s[k][c], s);
        Zf[(size_t)(row0 + r) * ZD + c] = (_Float16)s;
    }
}

// ---------------------------------------------------------------------------
// k3: upper-triangle tiles (ti <= tj), 128x128 per block, 4 waves.
// Single-pass f16 MFMA GEMM (16x16x32), operands direct from L2 (Z = 2 MiB,
// L2-resident). Epilogue: LDS-staged in two 64-col halves -> coalesced float4
// writes of logits [i,j], transposed [j,i], v = sigmoid(gumbel+L) into vbuf,
// row/col sums.
// ---------------------------------------------------------------------------
__global__ __launch_bounds__(256, 3) void k3_main(
    const _Float16* __restrict__ Zf, const float* __restrict__ noise,
    float* __restrict__ logits, float* __restrict__ vbuf,
    float* __restrict__ sums)
{
    const int tj = blockIdx.x, ti = blockIdx.y;
    if (ti > tj) return;
    const bool diag = (ti == tj);

    __shared__ float T[128][65];
    __shared__ float rs[128], cs[128];

    const int tid = threadIdx.x;
    const int lane = tid & 63;
    const int w = tid >> 6;
    const int wr = w >> 1, wc = w & 1;
    const int fr = lane & 15;     // fragment row (m/n within 16)
    const int kg = lane >> 4;     // k-group 0..3
    const int i0 = ti * 128, j0 = tj * 128;

    if (tid < 128) { rs[tid] = 0.0f; cs[tid] = 0.0f; }

    const _Float16* Ap = Zf + (size_t)(i0 + wr * 64) * ZD;
    const _Float16* Bp = Zf + (size_t)(j0 + wc * 64) * ZD;

    f32x4 acc[4][4];
    #pragma unroll
    for (int mf = 0; mf < 4; ++mf)
        #pragma unroll
        for (int nf = 0; nf < 4; ++nf)
            acc[mf][nf] = (f32x4)0.0f;

    #pragma unroll
    for (int kc = 0; kc < 4; ++kc) {
        const int ko = kc * 32 + kg * 8;
        f16x8 a[4], b[4];
        #pragma unroll
        for (int mf = 0; mf < 4; ++mf) {
            size_t off = (size_t)(mf * 16 + fr) * ZD + ko;
            a[mf] = *(const f16x8*)(Ap + off);
            b[mf] = *(const f16x8*)(Bp + off);
        }
        #pragma unroll
        for (int mf = 0; mf < 4; ++mf)
            #pragma unroll
            for (int nf = 0; nf < 4; ++nf)
                acc[mf][nf] = __builtin_amdgcn_mfma_f32_16x16x32_f16(a[mf], b[nf], acc[mf][nf], 0, 0, 0);
    }

    // ---- epilogue in two 64-column halves ----
    const int c4 = (tid & 15) * 4;        // local col group within half
    const int rbase = tid >> 4;           // 0..15

    #pragma unroll
    for (int half = 0; half < 2; ++half) {
        __syncthreads();   // previous half's readers done / rs,cs init visible
        if (wc == half) {
            #pragma unroll
            for (int mf = 0; mf < 4; ++mf)
                #pragma unroll
                for (int nf = 0; nf < 4; ++nf)
                    #pragma unroll
                    for (int r = 0; r < 4; ++r)
                        T[wr * 64 + mf * 16 + (lane >> 4) * 4 + r][nf * 16 + fr] = acc[mf][nf][r];
        }
        __syncthreads();

        float4 csum = make_float4(0.f, 0.f, 0.f, 0.f);
        for (int it = 0; it < 8; ++it) {
            const int r = rbase + it * 16;
            float4 L4 = *(const float4*)&T[r][c4];
            const size_t g = (size_t)(i0 + r) * N + j0 + half * 64 + c4;
            *(float4*)&logits[g] = L4;
            float4 u4 = *(const float4*)&noise[g];
            float vv[4];
            float rsum = 0.0f;
            const float* up = &u4.x;
            const float* Lp = &L4.x;
            float* cp = &csum.x;
            #pragma unroll
            for (int e = 0; e < 4; ++e) {
                float u = up[e];
                float eps = fmaf(-0.9998f, u, 0.9999f);   // eps in [1e-4, 1-1e-4]
                float om  = fmaf( 0.9998f, u, 0.0001f);   // 1 - eps
                float gate = __logf(eps) - __logf(om) + Lp[e];
                float v = 1.0f / (1.0f + __expf(-gate));
                if (diag && r >= half * 64 + c4 + e) v = 0.0f;  // strict upper
                vv[e] = v;
                rsum += v;
                cp[e] += v;
            }
            *(float4*)&vbuf[g] = make_float4(vv[0], vv[1], vv[2], vv[3]);
            rsum += __shfl_xor(rsum, 8, 16);
            rsum += __shfl_xor(rsum, 4, 16);
            rsum += __shfl_xor(rsum, 2, 16);
            rsum += __shfl_xor(rsum, 1, 16);
            if ((tid & 15) == 0) atomicAdd(&rs[r], rsum);
        }
        #pragma unroll
        for (int e = 0; e < 4; ++e)
            atomicAdd(&cs[half * 64 + c4 + e], (&csum.x)[e]);

        if (!diag) {
            for (int it = 0; it < 8; ++it) {
                const int idx = tid + it * 256;     // 0..2047
                const int c = idx >> 5;             // 0..63
                const int m4 = (idx & 31) * 4;
                float4 o = make_float4(T[m4][c], T[m4 + 1][c], T[m4 + 2][c], T[m4 + 3][c]);
                *(float4*)&logits[(size_t)(j0 + half * 64 + c) * N + i0 + m4] = o;
            }
        }
    }

    __syncthreads();
    if (tid < 128) {
        if (diag) {
            atomicAdd(&sums[i0 + tid], rs[tid] + cs[tid]);
        } else {
            atomicAdd(&sums[i0 + tid], rs[tid]);
            atomicAdd(&sums[j0 + tid], cs[tid]);
        }
    }
}

// ---------------------------------------------------------------------------
// k4: d = rsqrt(rowsum)
// ---------------------------------------------------------------------------
__global__ void k4_dvec(const float* __restrict__ sums, float* __restrict__ dvec)
{
    int i = blockIdx.x * 256 + threadIdx.x;
    if (i < N) dvec[i] = rsqrtf(sums[i]);
}

// ---------------------------------------------------------------------------
// k5: in-place normalize: adj[i,j] = v * d_i * d_j, mirror to [j,i],
// diagonal = d_i^2. Upper-triangle tiles only.
// ---------------------------------------------------------------------------
__global__ __launch_bounds__(256) void k5_norm(
    float* __restrict__ adj, const float* __restrict__ dvec)
{
    const int tj = blockIdx.x, ti = blockIdx.y;
    if (ti > tj) return;
    const bool diag = (ti == tj);
    __shared__ float T[128][65];
    const int tid = threadIdx.x;
    const int i0 = ti * 128, j0 = tj * 128;

    for (int it = 0; it < 16; ++it) {
        int w = tid + it * 256;
        int m = w >> 5;
        int n4 = (w & 31) << 2;
        size_t idx = (size_t)(i0 + m) * N + j0 + n4;
        float4 v4 = *(const float4*)&adj[idx];
        float dm = dvec[i0 + m];
        float4 o;
        o.x = v4.x * dm * dvec[j0 + n4 + 0];
        o.y = v4.y * dm * dvec[j0 + n4 + 1];
        o.z = v4.z * dm * dvec[j0 + n4 + 2];
        o.w = v4.w * dm * dvec[j0 + n4 + 3];
        *(float4*)&adj[idx] = o;   // diag tile: lower/diag components are 0, fixed below
        T[n4 + 0][m] = o.x; T[n4 + 1][m] = o.y;
        T[n4 + 2][m] = o.z; T[n4 + 3][m] = o.w;
    }
    __syncthreads();
    for (int it = 0; it < 64; ++it) {
        int w = tid + it * 256;
        int c = w >> 7, m = w & 127;
        if (!diag || m < c)
            adj[(size_t)(j0 + c) * N + i0 + m] = T[c][m];
    }
    if (diag && tid < 128) {
        float dm = dvec[i0 + tid];
        adj[(size_t)(i0 + tid) * N + i0 + tid] = dm * dm;
    }
}

// ---------------------------------------------------------------------------
extern "C" void kernel_launch(void* const* d_in, const int* in_sizes, int n_in,
                              void* d_out, int out_size, void* d_ws, size_t ws_size,
                              hipStream_t stream)
{
    const float* h     = (const float*)d_in[0];
    const float* W1    = (const float*)d_in[1];
    const float* b1    = (const float*)d_in[2];
    const float* W2    = (const float*)d_in[3];
    const float* b2    = (const float*)d_in[4];
    const float* noise = (const float*)d_in[5];

    float* adj    = (float*)d_out;                 // output 0: adj_norm [N,N]
    float* logits = adj + (size_t)N * N;           // output 1: adj_logits [N,N]

    _Float16* Zf = (_Float16*)d_ws;                // [N,128] f16 = 2 MiB
    float* sums  = (float*)(Zf + (size_t)N * ZD);  // [N]
    float* dvec  = sums + N;                       // [N]

    k1_mlp<<<128, 256, 0, stream>>>(h, W1, b1, W2, b2, Zf, sums);
    dim3 grid2(64, 64);
    k3_main<<<grid2, 256, 0, stream>>>(Zf, noise, logits, adj, sums);
    k4_dvec<<<32, 256, 0, stream>>>(sums, dvec);
    k5_norm<<<grid2, 256, 0, stream>>>(adj, dvec);
}

// Round 5
// 269.074 us; speedup vs baseline: 1.5278x; 1.2442x over previous
//
#include <hip/hip_runtime.h>
#include <hip/hip_bf16.h>
#include <math.h>

#define N 8192
#define ZD 128
#define NTILE 64            // N / 128
#define NUPPER 2080         // NTILE*(NTILE+1)/2

typedef __attribute__((ext_vector_type(8))) _Float16 f16x8;
typedef __attribute__((ext_vector_type(4))) _Float16 f16x4;
typedef __attribute__((ext_vector_type(4))) float f32x4;

__device__ __forceinline__ int upper_tile_index(int ti, int tj) {
    // tiles with row < ti: sum_{r<ti} (NTILE - r) = ti*NTILE - ti*(ti-1)/2
    return ti * NTILE - (ti * (ti - 1)) / 2 + (tj - ti);
}

// ---------------------------------------------------------------------------
// k1: Z = relu(h @ W1 + b1) @ W2 + b2 (fp32 math), stored as f16.
// 256 blocks x 32 rows; 8/16 independent FMA chains per thread (ILP),
// W[k][c] broadcast shared across the chains.
// Also initializes sums[i] = 1.0 (the fill_diagonal(1) contribution).
// ---------------------------------------------------------------------------
__global__ __launch_bounds__(256) void k1_mlp(
    const float* __restrict__ h, const float* __restrict__ W1,
    const float* __restrict__ b1, const float* __restrict__ W2,
    const float* __restrict__ b2, _Float16* __restrict__ Zf,
    float* __restrict__ sums)
{
    __shared__ float W1s[64][65];
    __shared__ float W2s[64][129];
    __shared__ float hs[32][68];
    __shared__ float Ts[32][68];
    __shared__ float b1s[64];
    __shared__ float b2s[128];
    const int tid = threadIdx.x;
    const int row0 = blockIdx.x * 32;

    if (tid < 32) sums[row0 + tid] = 1.0f;

    for (int e = tid; e < 64 * 64; e += 256) W1s[e >> 6][e & 63] = W1[e];
    for (int e = tid; e < 64 * 128; e += 256) W2s[e >> 7][e & 127] = W2[e];
    for (int e = tid; e < 32 * 64; e += 256) hs[e >> 6][e & 63] = h[(size_t)row0 * 64 + e];
    if (tid < 64) b1s[tid] = b1[tid];
    if (tid < 128) b2s[tid] = b2[tid];
    __syncthreads();

    // layer 1: 32x64 outputs, 8 rows per thread, shared weight broadcast
    {
        const int c = tid & 63;
        const int r0 = (tid >> 6) * 8;
        float s[8];
        #pragma unroll
        for (int j = 0; j < 8; ++j) s[j] = b1s[c];
        #pragma unroll
        for (int k0 = 0; k0 < 64; k0 += 4) {
            const float w0 = W1s[k0 + 0][c], w1 = W1s[k0 + 1][c];
            const float w2 = W1s[k0 + 2][c], w3 = W1s[k0 + 3][c];
            #pragma unroll
            for (int j = 0; j < 8; ++j) {
                f32x4 hv = *(const f32x4*)&hs[r0 + j][k0];
                s[j] = fmaf(hv[0], w0, s[j]);
                s[j] = fmaf(hv[1], w1, s[j]);
                s[j] = fmaf(hv[2], w2, s[j]);
                s[j] = fmaf(hv[3], w3, s[j]);
            }
        }
        #pragma unroll
        for (int j = 0; j < 8; ++j) Ts[r0 + j][c] = fmaxf(s[j], 0.0f);
    }
    __syncthreads();

    // layer 2: 32x128 outputs, 16 rows per thread
    {
        const int c = tid & 127;
        const int r0 = (tid >> 7) * 16;
        float s[16];
        #pragma unroll
        for (int j = 0; j < 16; ++j) s[j] = b2s[c];
        #pragma unroll
        for (int k0 = 0; k0 < 64; k0 += 4) {
            const float w0 = W2s[k0 + 0][c], w1 = W2s[k0 + 1][c];
            const float w2 = W2s[k0 + 2][c], w3 = W2s[k0 + 3][c];
            #pragma unroll
            for (int j = 0; j < 16; ++j) {
                f32x4 tv = *(const f32x4*)&Ts[r0 + j][k0];
                s[j] = fmaf(tv[0], w0, s[j]);
                s[j] = fmaf(tv[1], w1, s[j]);
                s[j] = fmaf(tv[2], w2, s[j]);
                s[j] = fmaf(tv[3], w3, s[j]);
            }
        }
        #pragma unroll
        for (int j = 0; j < 16; ++j)
            Zf[(size_t)(row0 + r0 + j) * ZD + c] = (_Float16)s[j];
    }
}

// ---------------------------------------------------------------------------
// k3: upper-triangle tiles (ti <= tj), 128x128 per block, 4 waves.
// Single-pass f16 MFMA GEMM (16x16x32), operands direct from L2 (Z = 2 MiB,
// kept resident because all streaming IO is nontemporal).
// Epilogue: LDS-staged in two 64-col halves -> coalesced f32x4 nt-writes of
// logits [i,j], transposed [j,i], v = sigmoid(gumbel+L) as f16 into compact
// per-tile vtile buffer, row/col sums.
// ---------------------------------------------------------------------------
__global__ __launch_bounds__(256, 3) void k3_main(
    const _Float16* __restrict__ Zf, const float* __restrict__ noise,
    float* __restrict__ logits, _Float16* __restrict__ vws,
    float* __restrict__ sums)
{
    const int tj = blockIdx.x, ti = blockIdx.y;
    if (ti > tj) return;
    const bool diag = (ti == tj);

    __shared__ float T[128][65];
    __shared__ float rs[128], cs[128];

    const int tid = threadIdx.x;
    const int lane = tid & 63;
    const int w = tid >> 6;
    const int wr = w >> 1, wc = w & 1;
    const int fr = lane & 15;     // fragment row (m/n within 16)
    const int kg = lane >> 4;     // k-group 0..3
    const int i0 = ti * 128, j0 = tj * 128;

    _Float16* __restrict__ vtile = vws + (size_t)upper_tile_index(ti, tj) * (128 * 128);

    if (tid < 128) { rs[tid] = 0.0f; cs[tid] = 0.0f; }

    const _Float16* Ap = Zf + (size_t)(i0 + wr * 64) * ZD;
    const _Float16* Bp = Zf + (size_t)(j0 + wc * 64) * ZD;

    f32x4 acc[4][4];
    #pragma unroll
    for (int mf = 0; mf < 4; ++mf)
        #pragma unroll
        for (int nf = 0; nf < 4; ++nf)
            acc[mf][nf] = (f32x4)0.0f;

    #pragma unroll
    for (int kc = 0; kc < 4; ++kc) {
        const int ko = kc * 32 + kg * 8;
        f16x8 a[4], b[4];
        #pragma unroll
        for (int mf = 0; mf < 4; ++mf) {
            size_t off = (size_t)(mf * 16 + fr) * ZD + ko;
            a[mf] = *(const f16x8*)(Ap + off);
            b[mf] = *(const f16x8*)(Bp + off);
        }
        #pragma unroll
        for (int mf = 0; mf < 4; ++mf)
            #pragma unroll
            for (int nf = 0; nf < 4; ++nf)
                acc[mf][nf] = __builtin_amdgcn_mfma_f32_16x16x32_f16(a[mf], b[nf], acc[mf][nf], 0, 0, 0);
    }

    // ---- epilogue in two 64-column halves ----
    const int c4 = (tid & 15) * 4;        // local col group within half
    const int rbase = tid >> 4;           // 0..15

    #pragma unroll
    for (int half = 0; half < 2; ++half) {
        __syncthreads();   // previous half's readers done / rs,cs init visible
        if (wc == half) {
            #pragma unroll
            for (int mf = 0; mf < 4; ++mf)
                #pragma unroll
                for (int nf = 0; nf < 4; ++nf)
                    #pragma unroll
                    for (int r = 0; r < 4; ++r)
                        T[wr * 64 + mf * 16 + (lane >> 4) * 4 + r][nf * 16 + fr] = acc[mf][nf][r];
        }
        __syncthreads();

        f32x4 csum = (f32x4)0.0f;
        #pragma unroll
        for (int it = 0; it < 8; ++it) {
            const int r = rbase + it * 16;
            f32x4 L4 = *(const f32x4*)&T[r][c4];
            const size_t g = (size_t)(i0 + r) * N + j0 + half * 64 + c4;
            __builtin_nontemporal_store(L4, (f32x4*)&logits[g]);
            f32x4 u4 = __builtin_nontemporal_load((const f32x4*)&noise[g]);
            float rsum = 0.0f;
            f16x4 vh;
            #pragma unroll
            for (int e = 0; e < 4; ++e) {
                float u = u4[e];
                float eps = fmaf(-0.9998f, u, 0.9999f);   // eps in [1e-4, 1-1e-4]
                float om  = fmaf( 0.9998f, u, 0.0001f);   // 1 - eps
                float gate = __logf(eps) - __logf(om) + L4[e];
                float v = 1.0f / (1.0f + __expf(-gate));
                if (diag && r >= half * 64 + c4 + e) v = 0.0f;  // strict upper
                vh[e] = (_Float16)v;
                rsum += v;
                csum[e] += v;
            }
            __builtin_nontemporal_store(vh, (f16x4*)&vtile[r * 128 + half * 64 + c4]);
            rsum += __shfl_xor(rsum, 8, 16);
            rsum += __shfl_xor(rsum, 4, 16);
            rsum += __shfl_xor(rsum, 2, 16);
            rsum += __shfl_xor(rsum, 1, 16);
            if ((tid & 15) == 0) atomicAdd(&rs[r], rsum);
        }
        #pragma unroll
        for (int e = 0; e < 4; ++e)
            atomicAdd(&cs[half * 64 + c4 + e], csum[e]);

        if (!diag) {
            #pragma unroll
            for (int it = 0; it < 8; ++it) {
                const int idx = tid + it * 256;     // 0..2047
                const int c = idx >> 5;             // 0..63
                const int m4 = (idx & 31) * 4;
                f32x4 o;
                o[0] = T[m4 + 0][c]; o[1] = T[m4 + 1][c];
                o[2] = T[m4 + 2][c]; o[3] = T[m4 + 3][c];
                __builtin_nontemporal_store(o, (f32x4*)&logits[(size_t)(j0 + half * 64 + c) * N + i0 + m4]);
            }
        }
    }

    __syncthreads();
    if (tid < 128) {
        if (diag) {
            atomicAdd(&sums[i0 + tid], rs[tid] + cs[tid]);
        } else {
            atomicAdd(&sums[i0 + tid], rs[tid]);
            atomicAdd(&sums[j0 + tid], cs[tid]);
        }
    }
}

// ---------------------------------------------------------------------------
// k4: d = rsqrt(rowsum)
// ---------------------------------------------------------------------------
__global__ void k4_dvec(const float* __restrict__ sums, float* __restrict__ dvec)
{
    int i = blockIdx.x * 256 + threadIdx.x;
    if (i < N) dvec[i] = rsqrtf(sums[i]);
}

// ---------------------------------------------------------------------------
// k5: adj[i,j] = v_f16 * d_i * d_j (from compact vtile), mirror to [j,i],
// diagonal = d_i^2. Upper-triangle tiles only. All global IO nontemporal.
// ---------------------------------------------------------------------------
__global__ __launch_bounds__(256, 4) void k5_norm(
    const _Float16* __restrict__ vws, float* __restrict__ adj,
    const float* __restrict__ dvec)
{
    const int tj = blockIdx.x, ti = blockIdx.y;
    if (ti > tj) return;
    const bool diag = (ti == tj);
    __shared__ float T[128][65];
    __shared__ float drow[128], dcol[128];
    const int tid = threadIdx.x;
    const int i0 = ti * 128, j0 = tj * 128;

    const _Float16* __restrict__ vtile = vws + (size_t)upper_tile_index(ti, tj) * (128 * 128);

    if (tid < 128) drow[tid] = dvec[i0 + tid];
    else dcol[tid - 128] = dvec[j0 + tid - 128];
    __syncthreads();

    #pragma unroll 4
    for (int it = 0; it < 16; ++it) {
        int w = tid + it * 256;
        int m = w >> 5;
        int n4 = (w & 31) << 2;
        f16x4 vh = __builtin_nontemporal_load((const f16x4*)&vtile[m * 128 + n4]);
        float dm = drow[m];
        f32x4 o;
        o[0] = (float)vh[0] * dm * dcol[n4 + 0];
        o[1] = (float)vh[1] * dm * dcol[n4 + 1];
        o[2] = (float)vh[2] * dm * dcol[n4 + 2];
        o[3] = (float)vh[3] * dm * dcol[n4 + 3];
        __builtin_nontemporal_store(o, (f32x4*)&adj[(size_t)(i0 + m) * N + j0 + n4]);
        T[n4 + 0][m] = o[0]; T[n4 + 1][m] = o[1];
        T[n4 + 2][m] = o[2]; T[n4 + 3][m] = o[3];
    }
    __syncthreads();
    #pragma unroll 4
    for (int it = 0; it < 64; ++it) {
        int w = tid + it * 256;
        int c = w >> 7, m = w & 127;
        if (!diag || m < c)
            __builtin_nontemporal_store(T[c][m], &adj[(size_t)(j0 + c) * N + i0 + m]);
    }
    if (diag && tid < 128) {
        float dm = drow[tid];
        adj[(size_t)(i0 + tid) * N + i0 + tid] = dm * dm;
    }
}

// ---------------------------------------------------------------------------
extern "C" void kernel_launch(void* const* d_in, const int* in_sizes, int n_in,
                              void* d_out, int out_size, void* d_ws, size_t ws_size,
                              hipStream_t stream)
{
    const float* h     = (const float*)d_in[0];
    const float* W1    = (const float*)d_in[1];
    const float* b1    = (const float*)d_in[2];
    const float* W2    = (const float*)d_in[3];
    const float* b2    = (const float*)d_in[4];
    const float* noise = (const float*)d_in[5];

    float* adj    = (float*)d_out;                 // output 0: adj_norm [N,N]
    float* logits = adj + (size_t)N * N;           // output 1: adj_logits [N,N]

    _Float16* Zf  = (_Float16*)d_ws;                           // [N,128] f16 = 2 MiB
    _Float16* vws = Zf + (size_t)N * ZD;                       // [2080*16384] f16 = 68 MiB
    float* sums   = (float*)(vws + (size_t)NUPPER * 128 * 128);// [N]
    float* dvec   = sums + N;                                  // [N]

    k1_mlp<<<256, 256, 0, stream>>>(h, W1, b1, W2, b2, Zf, sums);
    dim3 grid2(64, 64);
    k3_main<<<grid2, 256, 0, stream>>>(Zf, noise, logits, vws, sums);
    k4_dvec<<<32, 256, 0, stream>>>(sums, dvec);
    k5_norm<<<grid2, 256, 0, stream>>>(vws, adj, dvec);
}

// Round 6
// 230.239 us; speedup vs baseline: 1.7855x; 1.1687x over previous
//
#include <hip/hip_runtime.h>
#include <hip/hip_bf16.h>
#include <math.h>

#define N 8192
#define ZD 128
#define NTILE 64            // N / 128
#define NUPPER 2080         // NTILE*(NTILE+1)/2

typedef __attribute__((ext_vector_type(8))) _Float16 f16x8;
typedef __attribute__((ext_vector_type(4))) float f32x4;

__device__ __forceinline__ int tri_cum(int ti) {   // tiles before row ti
    return (ti * (2 * NTILE + 1 - ti)) / 2;        // ti*(129-ti)/2
}

__device__ __forceinline__ void tile_decode(int t, int& ti, int& tj) {
    int est = (int)((129.0f - sqrtf(16641.0f - 8.0f * (float)t)) * 0.5f);
    if (est < 0) est = 0;
    while (tri_cum(est) > t) --est;
    while (tri_cum(est + 1) <= t) ++est;
    ti = est;
    tj = est + (t - tri_cum(est));
}

// ---------------------------------------------------------------------------
// k1: Z = relu(h @ W1 + b1) @ W2 + b2 (fp32 math), stored as f16.
// Also initializes sums[i] = 1.0 (the fill_diagonal(1) contribution).
// ---------------------------------------------------------------------------
__global__ __launch_bounds__(256) void k1_mlp(
    const float* __restrict__ h, const float* __restrict__ W1,
    const float* __restrict__ b1, const float* __restrict__ W2,
    const float* __restrict__ b2, _Float16* __restrict__ Zf,
    float* __restrict__ sums)
{
    __shared__ float W1s[64][65];
    __shared__ float W2s[64][129];
    __shared__ float hs[32][68];
    __shared__ float Ts[32][68];
    __shared__ float b1s[64];
    __shared__ float b2s[128];
    const int tid = threadIdx.x;
    const int row0 = blockIdx.x * 32;

    if (tid < 32) sums[row0 + tid] = 1.0f;

    for (int e = tid; e < 64 * 64; e += 256) W1s[e >> 6][e & 63] = W1[e];
    for (int e = tid; e < 64 * 128; e += 256) W2s[e >> 7][e & 127] = W2[e];
    for (int e = tid; e < 32 * 64; e += 256) hs[e >> 6][e & 63] = h[(size_t)row0 * 64 + e];
    if (tid < 64) b1s[tid] = b1[tid];
    if (tid < 128) b2s[tid] = b2[tid];
    __syncthreads();

    // layer 1: 32x64 outputs, 8 rows per thread, shared weight broadcast
    {
        const int c = tid & 63;
        const int r0 = (tid >> 6) * 8;
        float s[8];
        #pragma unroll
        for (int j = 0; j < 8; ++j) s[j] = b1s[c];
        #pragma unroll
        for (int k0 = 0; k0 < 64; k0 += 4) {
            const float w0 = W1s[k0 + 0][c], w1 = W1s[k0 + 1][c];
            const float w2 = W1s[k0 + 2][c], w3 = W1s[k0 + 3][c];
            #pragma unroll
            for (int j = 0; j < 8; ++j) {
                f32x4 hv = *(const f32x4*)&hs[r0 + j][k0];
                s[j] = fmaf(hv[0], w0, s[j]);
                s[j] = fmaf(hv[1], w1, s[j]);
                s[j] = fmaf(hv[2], w2, s[j]);
                s[j] = fmaf(hv[3], w3, s[j]);
            }
        }
        #pragma unroll
        for (int j = 0; j < 8; ++j) Ts[r0 + j][c] = fmaxf(s[j], 0.0f);
    }
    __syncthreads();

    // layer 2: 32x128 outputs, 16 rows per thread
    {
        const int c = tid & 127;
        const int r0 = (tid >> 7) * 16;
        float s[16];
        #pragma unroll
        for (int j = 0; j < 16; ++j) s[j] = b2s[c];
        #pragma unroll
        for (int k0 = 0; k0 < 64; k0 += 4) {
            const float w0 = W2s[k0 + 0][c], w1 = W2s[k0 + 1][c];
            const float w2 = W2s[k0 + 2][c], w3 = W2s[k0 + 3][c];
            #pragma unroll
            for (int j = 0; j < 16; ++j) {
                f32x4 tv = *(const f32x4*)&Ts[r0 + j][k0];
                s[j] = fmaf(tv[0], w0, s[j]);
                s[j] = fmaf(tv[1], w1, s[j]);
                s[j] = fmaf(tv[2], w2, s[j]);
                s[j] = fmaf(tv[3], w3, s[j]);
            }
        }
        #pragma unroll
        for (int j = 0; j < 16; ++j)
            Zf[(size_t)(row0 + r0 + j) * ZD + c] = (_Float16)s[j];
    }
}

// ---------------------------------------------------------------------------
// k3: 2080 upper tiles (1-D grid), 128x128 per block, 4 waves.
// Single-pass f16 MFMA GEMM (16x16x32), operands direct from L2.
// Epilogue: LDS-staged in two 64-col halves -> coalesced f32x4 nt-writes of
// logits [i,j], transposed [j,i], v = sigmoid(gumbel+L) quantized to u8 into
// compact per-tile vtile buffer, row/col sums (fp32, pre-quantization).
// ---------------------------------------------------------------------------
__global__ __launch_bounds__(256, 3) void k3_main(
    const _Float16* __restrict__ Zf, const float* __restrict__ noise,
    float* __restrict__ logits, unsigned char* __restrict__ vws,
    float* __restrict__ sums)
{
    int ti, tj;
    tile_decode(blockIdx.x, ti, tj);
    const bool diag = (ti == tj);

    __shared__ float T[128][65];
    __shared__ float rs[128], cs[128];

    const int tid = threadIdx.x;
    const int lane = tid & 63;
    const int w = tid >> 6;
    const int wr = w >> 1, wc = w & 1;
    const int fr = lane & 15;     // fragment row (m/n within 16)
    const int kg = lane >> 4;     // k-group 0..3
    const int i0 = ti * 128, j0 = tj * 128;

    unsigned char* __restrict__ vtile = vws + (size_t)blockIdx.x * (128 * 128);

    if (tid < 128) { rs[tid] = 0.0f; cs[tid] = 0.0f; }

    const _Float16* Ap = Zf + (size_t)(i0 + wr * 64) * ZD;
    const _Float16* Bp = Zf + (size_t)(j0 + wc * 64) * ZD;

    f32x4 acc[4][4];
    #pragma unroll
    for (int mf = 0; mf < 4; ++mf)
        #pragma unroll
        for (int nf = 0; nf < 4; ++nf)
            acc[mf][nf] = (f32x4)0.0f;

    #pragma unroll
    for (int kc = 0; kc < 4; ++kc) {
        const int ko = kc * 32 + kg * 8;
        f16x8 a[4], b[4];
        #pragma unroll
        for (int mf = 0; mf < 4; ++mf) {
            size_t off = (size_t)(mf * 16 + fr) * ZD + ko;
            a[mf] = *(const f16x8*)(Ap + off);
            b[mf] = *(const f16x8*)(Bp + off);
        }
        #pragma unroll
        for (int mf = 0; mf < 4; ++mf)
            #pragma unroll
            for (int nf = 0; nf < 4; ++nf)
                acc[mf][nf] = __builtin_amdgcn_mfma_f32_16x16x32_f16(a[mf], b[nf], acc[mf][nf], 0, 0, 0);
    }

    // ---- epilogue in two 64-column halves ----
    const int c4 = (tid & 15) * 4;        // local col group within half
    const int rbase = tid >> 4;           // 0..15

    #pragma unroll
    for (int half = 0; half < 2; ++half) {
        __syncthreads();   // previous half's readers done / rs,cs init visible
        if (wc == half) {
            #pragma unroll
            for (int mf = 0; mf < 4; ++mf)
                #pragma unroll
                for (int nf = 0; nf < 4; ++nf)
                    #pragma unroll
                    for (int r = 0; r < 4; ++r)
                        T[wr * 64 + mf * 16 + (lane >> 4) * 4 + r][nf * 16 + fr] = acc[mf][nf][r];
        }
        __syncthreads();

        f32x4 csum = (f32x4)0.0f;
        #pragma unroll
        for (int it = 0; it < 8; ++it) {
            const int r = rbase + it * 16;
            f32x4 L4 = *(const f32x4*)&T[r][c4];
            const size_t g = (size_t)(i0 + r) * N + j0 + half * 64 + c4;
            __builtin_nontemporal_store(L4, (f32x4*)&logits[g]);
            f32x4 u4 = __builtin_nontemporal_load((const f32x4*)&noise[g]);
            float rsum = 0.0f;
            unsigned q = 0;
            #pragma unroll
            for (int e = 0; e < 4; ++e) {
                float u = u4[e];
                float eps = fmaf(-0.9998f, u, 0.9999f);   // eps in [1e-4, 1-1e-4]
                float om  = fmaf( 0.9998f, u, 0.0001f);   // 1 - eps
                float gate = __logf(eps) - __logf(om) + L4[e];
                float v = 1.0f / (1.0f + __expf(-gate));
                if (diag && r >= half * 64 + c4 + e) v = 0.0f;  // strict upper
                q |= ((unsigned)(int)rintf(v * 255.0f)) << (8 * e);
                rsum += v;
                csum[e] += v;
            }
            __builtin_nontemporal_store(q, (unsigned*)&vtile[r * 128 + half * 64 + c4]);
            atomicAdd(&rs[r], rsum);     // fire-and-forget, 16 lanes/row
        }
        #pragma unroll
        for (int e = 0; e < 4; ++e)
            atomicAdd(&cs[half * 64 + c4 + e], csum[e]);

        if (!diag) {
            #pragma unroll
            for (int it = 0; it < 8; ++it) {
                const int idx = tid + it * 256;     // 0..2047
                const int c = idx >> 5;             // 0..63
                const int m4 = (idx & 31) * 4;
                f32x4 o;
                o[0] = T[m4 + 0][c]; o[1] = T[m4 + 1][c];
                o[2] = T[m4 + 2][c]; o[3] = T[m4 + 3][c];
                __builtin_nontemporal_store(o, (f32x4*)&logits[(size_t)(j0 + half * 64 + c) * N + i0 + m4]);
            }
        }
    }

    __syncthreads();
    if (tid < 128) {
        if (diag) {
            atomicAdd(&sums[i0 + tid], rs[tid] + cs[tid]);
        } else {
            atomicAdd(&sums[i0 + tid], rs[tid]);
            atomicAdd(&sums[j0 + tid], cs[tid]);
        }
    }
}

// ---------------------------------------------------------------------------
// k5: adj[i,j] = v_u8/255 * d_i * d_j (from compact vtile), mirror to [j,i],
// diagonal = d_i^2. d = rsqrt(sums) recomputed per block (L2-resident sums).
// T is [col][row] with 68-stride for 16B-aligned vectorized mirror stores.
// ---------------------------------------------------------------------------
__global__ __launch_bounds__(256, 4) void k5_norm(
    const unsigned char* __restrict__ vws, float* __restrict__ adj,
    const float* __restrict__ sums)
{
    int ti, tj;
    tile_decode(blockIdx.x, ti, tj);
    const bool diag = (ti == tj);
    __shared__ float T[128][68];
    __shared__ float drow[128], dcol[128];
    const int tid = threadIdx.x;
    const int i0 = ti * 128, j0 = tj * 128;

    const unsigned char* __restrict__ vtile = vws + (size_t)blockIdx.x * (128 * 128);

    if (tid < 128) drow[tid] = rsqrtf(sums[i0 + tid]);
    else dcol[tid - 128] = rsqrtf(sums[j0 + tid - 128]);
    __syncthreads();

    const float inv255 = 1.0f / 255.0f;
    #pragma unroll 4
    for (int it = 0; it < 16; ++it) {
        int w = tid + it * 256;
        int m = w >> 5;
        int n4 = (w & 31) << 2;
        unsigned q = __builtin_nontemporal_load((const unsigned*)&vtile[m * 128 + n4]);
        float dm = drow[m];
        f32x4 o;
        o[0] = (float)(q & 255)         * inv255 * dm * dcol[n4 + 0];
        o[1] = (float)((q >> 8) & 255)  * inv255 * dm * dcol[n4 + 1];
        o[2] = (float)((q >> 16) & 255) * inv255 * dm * dcol[n4 + 2];
        o[3] = (float)(q >> 24)         * inv255 * dm * dcol[n4 + 3];
        __builtin_nontemporal_store(o, (f32x4*)&adj[(size_t)(i0 + m) * N + j0 + n4]);
        T[n4 + 0][m] = o[0]; T[n4 + 1][m] = o[1];
        T[n4 + 2][m] = o[2]; T[n4 + 3][m] = o[3];
    }
    __syncthreads();
    // mirror: adj[j0+c][i0+m4..m4+3] = T[c][m4..m4+3] (contiguous, 16B aligned)
    #pragma unroll 4
    for (int it = 0; it < 16; ++it) {
        int w = tid + it * 256;
        int c = w >> 5;
        int m4 = (w & 31) << 2;
        f32x4 o = *(const f32x4*)&T[c][m4];
        if (!diag) {
            __builtin_nontemporal_store(o, (f32x4*)&adj[(size_t)(j0 + c) * N + i0 + m4]);
        } else {
            // only strictly-lower part (m < c); handle partial vectors scalar
            #pragma unroll
            for (int e = 0; e < 4; ++e)
                if (m4 + e < c)
                    adj[(size_t)(j0 + c) * N + i0 + m4 + e] = o[e];
        }
    }
    if (diag && tid < 128) {
        float dm = drow[tid];
        adj[(size_t)(i0 + tid) * N + i0 + tid] = dm * dm;
    }
}

// ---------------------------------------------------------------------------
extern "C" void kernel_launch(void* const* d_in, const int* in_sizes, int n_in,
                              void* d_out, int out_size, void* d_ws, size_t ws_size,
                              hipStream_t stream)
{
    const float* h     = (const float*)d_in[0];
    const float* W1    = (const float*)d_in[1];
    const float* b1    = (const float*)d_in[2];
    const float* W2    = (const float*)d_in[3];
    const float* b2    = (const float*)d_in[4];
    const float* noise = (const float*)d_in[5];

    float* adj    = (float*)d_out;                 // output 0: adj_norm [N,N]
    float* logits = adj + (size_t)N * N;           // output 1: adj_logits [N,N]

    _Float16* Zf       = (_Float16*)d_ws;                      // [N,128] f16 = 2 MiB
    unsigned char* vws = (unsigned char*)(Zf + (size_t)N * ZD);// [2080*16384] u8 = 34 MiB
    float* sums        = (float*)(vws + (size_t)NUPPER * 128 * 128); // [N]

    k1_mlp<<<256, 256, 0, stream>>>(h, W1, b1, W2, b2, Zf, sums);
    k3_main<<<NUPPER, 256, 0, stream>>>(Zf, noise, logits, vws, sums);
    k5_norm<<<NUPPER, 256, 0, stream>>>(vws, adj, sums);
}